// Round 15
// baseline (237.411 us; speedup 1.0000x reference)
//
#include <hip/hip_runtime.h>
#include <math.h>

#define NN 100000
#define NE 1600000
#define D 128
#define BN_EPS 1e-5f
#define GSZ4 25000   // hist/scatter group node range (4 groups)
#define NCH 64       // edge chunks
#define CH 25000     // NE / NCH
#define HW8 6250     // words per hist half (4 nodes/word, 8-bit packed)
#define HSTR 12500   // words per (group,chunk) slice: [0,HW8)=cnt, [HW8,2*HW8)=deg
#define NPART 98     // ceil(NN/1024) part chunks
#define NCVT 192     // extra hist-kernel blocks doing x->bf16

typedef __attribute__((ext_vector_type(8))) short short8;
typedef __attribute__((ext_vector_type(4))) float f32x4;

// ws layout (bytes):
// dinv   [0,        400000)
// cnt    [400000,   800000)
// off    [800000,  1200000)
// part   [1200000, 1202048)
// sums8  [1202048, 1210240)   8 x 256 floats ([0..127]=s, [128..255]=s2)
// esrc   [1210368, 7610368)   src per CSR slot
// hist   [7610368, 20410368)  12.8 MB (4 groups x 64 chunks x 12500 words)
// xh     [20410368,46010368)  x bf16 packed [NN][64] uints; reused as relu-bf16 rh
// Wht    [46010368,46043136)
// d_out doubles as bf16 agg buffer between gather and gemm.

__device__ __forceinline__ unsigned bf_rne(float f) {
    unsigned u = __float_as_uint(f);
    return (u + 0x7fffu + ((u >> 16) & 1u)) >> 16;
}
__device__ __forceinline__ unsigned pk2(float lo, float hi) {
    return bf_rne(lo) | (bf_rne(hi) << 16);
}

// ---- kernel 1: heterogeneous: blocks<256 LDS histograms; blocks>=256 x->bf16 ----
__global__ __launch_bounds__(1024) void k_hist(const int* __restrict__ ei,
                                               unsigned* __restrict__ hist,
                                               const float* __restrict__ x,
                                               unsigned* __restrict__ xh) {
    __shared__ unsigned loc[HSTR];  // 50 KB
    if (blockIdx.x < 256) {
        const int g = blockIdx.x & 3;
        const int t = blockIdx.x >> 2;
        const int lo = g * GSZ4, hi = lo + GSZ4;
        for (int j = threadIdx.x; j < HSTR; j += 1024) loc[j] = 0u;
        __syncthreads();
        const int end = t * CH + CH;
        for (int i = t * CH + threadIdx.x; i < end; i += 1024) {
            int r = __builtin_nontemporal_load(ei + i);
            int c = __builtin_nontemporal_load(ei + NE + i);
            if (r != c) {
                if (c >= lo && c < hi) {
                    int q = c - lo;
                    atomicAdd(&loc[q >> 2], 1u << ((q & 3) << 3));
                }
                if (r >= lo && r < hi) {
                    int q = r - lo;
                    atomicAdd(&loc[HW8 + (q >> 2)], 1u << ((q & 3) << 3));
                }
            }
        }
        __syncthreads();
        unsigned* dst = hist + (unsigned)(g * NCH + t) * HSTR;
        for (int j = threadIdx.x; j < HSTR; j += 1024) dst[j] = loc[j];
    } else {
        // x -> bf16 packed, f32x4 (16B) loads, grid-stride
        int idx = (blockIdx.x - 256) * 1024 + threadIdx.x;
        const int stride = NCVT * 1024;
        for (; idx < NN * 32; idx += stride) {
            f32x4 v = __builtin_nontemporal_load((const f32x4*)x + idx);
            uint2 o;
            o.x = pk2(v.x, v.y);
            o.y = pk2(v.z, v.w);
            ((uint2*)xh)[idx] = o;
        }
    }
}

// ---- kernel 2: reduce hists -> cnt, dinv; chunk prefixes; scan1; cvtw; zero ----
__global__ __launch_bounds__(256) void k_reduce(unsigned* __restrict__ hist,
                                                unsigned* __restrict__ cnt,
                                                float* __restrict__ dinv,
                                                const float* __restrict__ W,
                                                unsigned short* __restrict__ Wht,
                                                unsigned* __restrict__ part,
                                                float* __restrict__ sums8) {
    __shared__ unsigned ps[256];
    int id = blockIdx.x * 256 + threadIdx.x;
    unsigned mysum = 0;
    if (id < 4 * HW8) {
        int g = id / HW8;
        int w = id - g * HW8;
        unsigned base = (unsigned)(g * NCH) * HSTR + w;
        unsigned r0 = 0, r1 = 0, r2 = 0, r3 = 0;
        unsigned s0 = 0, s1 = 0, s2 = 0, s3 = 0;
        for (int t = 0; t < NCH; ++t) {
            unsigned idx = base + (unsigned)t * HSTR;
            unsigned v = hist[idx];
            hist[idx] = r0 | (r1 << 8) | (r2 << 16) | (r3 << 24);  // excl prefix
            r0 += v & 255u; r1 += (v >> 8) & 255u;
            r2 += (v >> 16) & 255u; r3 += v >> 24;
            unsigned d = hist[idx + HW8];
            s0 += d & 255u; s1 += (d >> 8) & 255u;
            s2 += (d >> 16) & 255u; s3 += d >> 24;
        }
        int n0 = 4 * id;
        cnt[n0]     = r0; cnt[n0 + 1] = r1; cnt[n0 + 2] = r2; cnt[n0 + 3] = r3;
        dinv[n0]     = rsqrtf((float)(s0 + 1u));  // +1 self-loop
        dinv[n0 + 1] = rsqrtf((float)(s1 + 1u));
        dinv[n0 + 2] = rsqrtf((float)(s2 + 1u));
        dinv[n0 + 3] = rsqrtf((float)(s3 + 1u));
        mysum = r0 + r1 + r2 + r3;
    } else {
        int i = id - 4 * HW8;
        if (i < D * D) {           // cvtw: W[k][c] -> Wht[c][k]
            int k = i >> 7, c = i & 127;
            Wht[c * D + k] = (unsigned short)bf_rne(W[i]);
        } else if (i < D * D + 2048) {
            sums8[i - D * D] = 0.f;
        }
    }
    if (blockIdx.x < NPART) {  // scan1: per-1024-node chunk sums
        ps[threadIdx.x] = mysum;
        __syncthreads();
        for (int o = 128; o > 0; o >>= 1) {
            if (threadIdx.x < o) ps[threadIdx.x] += ps[threadIdx.x + o];
            __syncthreads();
        }
        if (threadIdx.x == 0) part[blockIdx.x] = ps[0];
    }
}

// ------- scan step: per-node exclusive offsets; each block scans part itself ----
__global__ __launch_bounds__(256) void k_scan3(const unsigned* __restrict__ cnt,
                                               const unsigned* __restrict__ part,
                                               unsigned* __restrict__ off) {
    __shared__ unsigned pp[128];
    __shared__ unsigned s[256];
    const int t = threadIdx.x;
    if (t < 128) pp[t] = (t < NPART) ? part[t] : 0u;
    __syncthreads();
    for (int o = 1; o < 128; o <<= 1) {  // inclusive scan of partials
        unsigned add = (t < 128 && t >= o) ? pp[t - o] : 0u;
        __syncthreads();
        if (t < 128) pp[t] += add;
        __syncthreads();
    }
    const unsigned base = (blockIdx.x == 0) ? 0u : pp[blockIdx.x - 1];

    const int n0 = (blockIdx.x * 256 + t) * 4;
    unsigned c0 = 0, c1 = 0, c2 = 0, c3 = 0;
    if (n0 + 3 < NN) {
        uint4 v = *(const uint4*)&cnt[n0];
        c0 = v.x; c1 = v.y; c2 = v.z; c3 = v.w;
    } else if (n0 < NN) {
        c0 = cnt[n0];
        if (n0 + 1 < NN) c1 = cnt[n0 + 1];
        if (n0 + 2 < NN) c2 = cnt[n0 + 2];
    }
    unsigned mysum = c0 + c1 + c2 + c3;
    s[t] = mysum;
    __syncthreads();
    for (int o = 1; o < 256; o <<= 1) {
        unsigned add = (t >= o) ? s[t - o] : 0u;
        __syncthreads();
        s[t] += add;
        __syncthreads();
    }
    unsigned e = base + s[t] - mysum;
    if (n0 < NN) {
        off[n0] = e;
        if (n0 + 1 < NN) off[n0 + 1] = e + c0;
        if (n0 + 2 < NN) off[n0 + 2] = e + c0 + c1;
        if (n0 + 3 < NN) off[n0 + 3] = e + c0 + c1 + c2;
    }
}

// ---- kernel 3: 4-group scatter via packed 16-bit LDS cursors, 1024 thr ---------
__global__ __launch_bounds__(1024) void k_scatter(const int* __restrict__ ei,
                                                  const unsigned* __restrict__ off,
                                                  const unsigned* __restrict__ hist,
                                                  int* __restrict__ esrc) {
    __shared__ unsigned curs[GSZ4 / 2];  // 50 KB packed
    const int g = blockIdx.x & 3;
    const int t = blockIdx.x >> 2;
    const int lo = g * GSZ4, hi = lo + GSZ4;
    const unsigned* hb = hist + (unsigned)(g * NCH + t) * HSTR;
    for (int j = threadIdx.x; j < GSZ4 / 2; j += 1024) {
        unsigned hv = hb[j >> 1];
        unsigned sh = (j & 1) << 4;  // bytes {0,1} or {2,3}
        unsigned p0 = (hv >> sh) & 255u;
        unsigned p1 = (hv >> (sh + 8)) & 255u;
        curs[j] = p0 | (p1 << 16);
    }
    __syncthreads();
    const int end = t * CH + CH;
    for (int i = t * CH + threadIdx.x; i < end; i += 1024) {
        int r = __builtin_nontemporal_load(ei + i);
        int c = __builtin_nontemporal_load(ei + NE + i);
        if (r == c || c < lo || c >= hi) continue;
        int q = c - lo;
        unsigned sh = (q & 1) << 4;
        unsigned old = atomicAdd(&curs[q >> 1], 1u << sh);  // LDS atomic
        unsigned pos = off[c] + ((old >> sh) & 0xffffu);
        esrc[pos] = r;  // L2-local slice, plain store
    }
}

// -------- kernel 4: gather, half-wave rows: each 32-lane half loads one full ----
// 256B row as uint2 (8B/lane) -> one load instr covers TWO edges' rows per wave.
// Lane l (h=l>>5, m=l&31) accumulates channels 4m..4m+3 of its half's edges;
// cross-half shfl_xor(32) merge at the end; half 0 owns self-term and store.
__global__ __launch_bounds__(256) void k_gather(const unsigned* __restrict__ xh,
                                                const float* __restrict__ dinv,
                                                const unsigned* __restrict__ off,
                                                const unsigned* __restrict__ cnt,
                                                const int* __restrict__ esrc,
                                                unsigned* __restrict__ outh) {
    const int lane = threadIdx.x & 63;
    const int wave = threadIdx.x >> 6;
    const int h = lane >> 5, m = lane & 31;
    const int c = blockIdx.x * 4 + wave;
    if (c >= NN) return;

    const float dc = dinv[c];
    const unsigned* xrow_c = xh + c * 64 + 2 * m;
    uint2 xc = *(const uint2*)xrow_c;
    const float selfw = (h == 0) ? dc : 0.f;
    float a0 = selfw * __uint_as_float(xc.x << 16);
    float a1 = selfw * __uint_as_float(xc.x & 0xffff0000u);
    float a2 = selfw * __uint_as_float(xc.y << 16);
    float a3 = selfw * __uint_as_float(xc.y & 0xffff0000u);

    const int base = off[c];
    const int n = cnt[c];
    int i = 0;
    // unroll: 8 pairs = 16 edges, 8 in flight per half
    for (; i + 16 <= n; i += 16) {
        int sv[8]; float wv[8]; uint2 pv[8];
        #pragma unroll
        for (int j = 0; j < 8; ++j) sv[j] = esrc[base + i + 2 * j + h];
        #pragma unroll
        for (int j = 0; j < 8; ++j) wv[j] = dinv[sv[j]];
        #pragma unroll
        for (int j = 0; j < 8; ++j) pv[j] = *(const uint2*)(xh + sv[j] * 64 + 2 * m);
        #pragma unroll
        for (int j = 0; j < 8; ++j) {
            a0 = fmaf(wv[j], __uint_as_float(pv[j].x << 16), a0);
            a1 = fmaf(wv[j], __uint_as_float(pv[j].x & 0xffff0000u), a1);
            a2 = fmaf(wv[j], __uint_as_float(pv[j].y << 16), a2);
            a3 = fmaf(wv[j], __uint_as_float(pv[j].y & 0xffff0000u), a3);
        }
    }
    // guarded pair loop for the remainder
    for (; i < n; i += 2) {
        const int e = i + h;
        const int idx = base + ((e < n) ? e : i);  // in-bounds fallback
        int s = esrc[idx];
        float w = (e < n) ? dinv[s] : 0.f;
        uint2 p = *(const uint2*)(xh + s * 64 + 2 * m);
        a0 = fmaf(w, __uint_as_float(p.x << 16), a0);
        a1 = fmaf(w, __uint_as_float(p.x & 0xffff0000u), a1);
        a2 = fmaf(w, __uint_as_float(p.y << 16), a2);
        a3 = fmaf(w, __uint_as_float(p.y & 0xffff0000u), a3);
    }
    // merge halves
    a0 += __shfl_xor(a0, 32);
    a1 += __shfl_xor(a1, 32);
    a2 += __shfl_xor(a2, 32);
    a3 += __shfl_xor(a3, 32);
    if (h == 0) {
        uint2 o;
        o.x = pk2(a0 * dc, a1 * dc);
        o.y = pk2(a2 * dc, a3 * dc);
        *(uint2*)(outh + c * 64 + 2 * m) = o;
    }
}

// ---- kernel 5: MFMA GEMM (bf16 A direct) + bias + ReLU -> bf16 rh + BN stats ---
__global__ __launch_bounds__(256, 1) void k_gemm(const unsigned short* __restrict__ aggh,
                                                 unsigned short* __restrict__ rh,
                                                 const unsigned short* __restrict__ Wht,
                                                 const float* __restrict__ b,
                                                 float* __restrict__ sums8) {
    __shared__ float sums_lds[256];
    const int lane = threadIdx.x & 63;
    const int wv = threadIdx.x >> 6;
    const int l15 = lane & 15, l4 = lane >> 4;

    if (threadIdx.x < 256) sums_lds[threadIdx.x] = 0.f;
    __syncthreads();

    short8 bfr[8][4];
    #pragma unroll
    for (int n = 0; n < 8; ++n)
        #pragma unroll
        for (int kk = 0; kk < 4; ++kk)
            bfr[n][kk] = *(const short8*)(Wht + (n * 16 + l15) * D + kk * 32 + l4 * 8);

    float bias8[8];
    #pragma unroll
    for (int n = 0; n < 8; ++n) bias8[n] = b[n * 16 + l15];

    float sl[8], s2l[8];
    #pragma unroll
    for (int n = 0; n < 8; ++n) { sl[n] = 0.f; s2l[n] = 0.f; }

    const int gw = blockIdx.x * 4 + wv;
    #pragma unroll
    for (int t = 0; t < 2; ++t) {
        const int tile = gw * 2 + t;
        if (tile < NN / 16) {
            const int row0 = tile * 16;
            short8 af[4];
            #pragma unroll
            for (int kk = 0; kk < 4; ++kk)
                af[kk] = *(const short8*)(aggh + (row0 + l15) * D + kk * 32 + l4 * 8);
            f32x4 acc[8];
            #pragma unroll
            for (int n = 0; n < 8; ++n) acc[n] = (f32x4){0.f, 0.f, 0.f, 0.f};
            #pragma unroll
            for (int n = 0; n < 8; ++n)
                #pragma unroll
                for (int kk = 0; kk < 4; ++kk)
                    acc[n] = __builtin_amdgcn_mfma_f32_16x16x32_bf16(af[kk], bfr[n][kk],
                                                                     acc[n], 0, 0, 0);
            #pragma unroll
            for (int n = 0; n < 8; ++n)
                #pragma unroll
                for (int j = 0; j < 4; ++j) {
                    int row = row0 + l4 * 4 + j;
                    float v = fmaxf(acc[n][j] + bias8[n], 0.f);
                    rh[row * D + n * 16 + l15] = (unsigned short)bf_rne(v);
                    sl[n] += v;
                    s2l[n] = fmaf(v, v, s2l[n]);
                }
        }
    }

    #pragma unroll
    for (int n = 0; n < 8; ++n) {
        float a = sl[n], q = s2l[n];
        a += __shfl_xor(a, 16); a += __shfl_xor(a, 32);
        q += __shfl_xor(q, 16); q += __shfl_xor(q, 32);
        if (l4 == 0) {
            atomicAdd(&sums_lds[n * 16 + l15], a);
            atomicAdd(&sums_lds[128 + n * 16 + l15], q);
        }
    }
    __syncthreads();
    if (threadIdx.x < 256)
        unsafeAtomicAdd(&sums8[(blockIdx.x & 7) * 256 + threadIdx.x],
                        sums_lds[threadIdx.x]);
}

// ------------- kernel 6: out = rh_bf16 * scale + shift (BN affine) --------------
__global__ __launch_bounds__(256) void k_apply(const unsigned* __restrict__ rh,
                                               float* __restrict__ out,
                                               const float* __restrict__ gamma,
                                               const float* __restrict__ beta,
                                               const float* __restrict__ sums8) {
    const float invN = 1.f / (float)NN;
    const int tid = blockIdx.x * blockDim.x + threadIdx.x;
    const int stride = gridDim.x * blockDim.x;
    const int c4 = (tid & 31) * 4;

    float4 s4 = make_float4(0.f, 0.f, 0.f, 0.f);
    float4 q4 = make_float4(0.f, 0.f, 0.f, 0.f);
    #pragma unroll
    for (int k = 0; k < 8; ++k) {
        float4 a = *(const float4*)&sums8[k * 256 + c4];
        float4 q = *(const float4*)&sums8[k * 256 + 128 + c4];
        s4.x += a.x; s4.y += a.y; s4.z += a.z; s4.w += a.w;
        q4.x += q.x; q4.y += q.y; q4.z += q.z; q4.w += q.w;
    }
    float4 g4 = *(const float4*)&gamma[c4];
    float4 be = *(const float4*)&beta[c4];

    float mx = s4.x * invN, my = s4.y * invN, mz = s4.z * invN, mw = s4.w * invN;
    float scx = g4.x * rsqrtf(fmaxf(q4.x * invN - mx * mx, 0.f) + BN_EPS);
    float scy = g4.y * rsqrtf(fmaxf(q4.y * invN - my * my, 0.f) + BN_EPS);
    float scz = g4.z * rsqrtf(fmaxf(q4.z * invN - mz * mz, 0.f) + BN_EPS);
    float scw = g4.w * rsqrtf(fmaxf(q4.w * invN - mw * mw, 0.f) + BN_EPS);
    float shx = be.x - mx * scx, shy = be.y - my * scy;
    float shz = be.z - mz * scz, shw = be.w - mw * scw;

    for (int idx = tid; idx < NN * (D / 4); idx += stride) {
        const int row = idx >> 5;
        uint2 p = *(const uint2*)&rh[row * 64 + (tid & 31) * 2];
        float4 a;
        a.x = __uint_as_float(p.x << 16);
        a.y = __uint_as_float(p.x & 0xffff0000u);
        a.z = __uint_as_float(p.y << 16);
        a.w = __uint_as_float(p.y & 0xffff0000u);
        a.x = a.x * scx + shx;
        a.y = a.y * scy + shy;
        a.z = a.z * scz + shz;
        a.w = a.w * scw + shw;
        ((float4*)out)[idx] = a;
    }
}

extern "C" void kernel_launch(void* const* d_in, const int* in_sizes, int n_in,
                              void* d_out, int out_size, void* d_ws, size_t ws_size,
                              hipStream_t stream) {
    const float* x     = (const float*)d_in[0];
    const int*   ei    = (const int*)d_in[1];
    const float* W     = (const float*)d_in[2];
    const float* b     = (const float*)d_in[3];
    const float* gamma = (const float*)d_in[4];
    const float* beta  = (const float*)d_in[5];
    float*       out   = (float*)d_out;

    char* ws = (char*)d_ws;
    float*          dinv  = (float*)ws;
    unsigned*       cnt   = (unsigned*)(ws + 400000);
    unsigned*       off   = (unsigned*)(ws + 800000);
    unsigned*       part  = (unsigned*)(ws + 1200000);
    float*          sums8 = (float*)(ws + 1202048);
    int*            esrc  = (int*)(ws + 1210368);
    unsigned*       hist  = (unsigned*)(ws + 7610368);   // 12.8 MB
    unsigned*       xh    = (unsigned*)(ws + 20410368);  // 25.6 MB; rh after gather
    unsigned short* Wht   = (unsigned short*)(ws + 46010368);

    k_hist<<<256 + NCVT, 1024, 0, stream>>>(ei, hist, x, xh);
    k_reduce<<<(4 * HW8 + D * D + 2048 + 255) / 256, 256, 0, stream>>>(hist, cnt, dinv, W, Wht, part, sums8);
    k_scan3<<<NPART, 256, 0, stream>>>(cnt, part, off);
    k_scatter<<<NCH * 4, 1024, 0, stream>>>(ei, off, hist, esrc);
    k_gather<<<25000, 256, 0, stream>>>(xh, dinv, off, cnt, esrc, (unsigned*)out);
    k_gemm<<<782, 256, 0, stream>>>((const unsigned short*)out, (unsigned short*)xh, Wht, b, sums8);
    k_apply<<<2048, 256, 0, stream>>>(xh, out, gamma, beta, sums8);
}

// Round 16
// 201.418 us; speedup vs baseline: 1.1787x; 1.1787x over previous
//
#include <hip/hip_runtime.h>
#include <math.h>

#define NN 100000
#define NE 1600000
#define D 128
#define BN_EPS 1e-5f
#define GSZ4 25000   // hist/scatter group node range (4 groups)
#define NCH 64       // edge chunks
#define CH 25000     // NE / NCH
#define HW8 6250     // words per hist half (4 nodes/word, 8-bit packed)
#define HSTR 12500   // words per (group,chunk) slice: [0,HW8)=cnt, [HW8,2*HW8)=deg
#define NPART 98     // ceil(NN/1024) part chunks
#define NCVT 192     // extra hist-kernel blocks doing x->bf16

typedef __attribute__((ext_vector_type(8))) short short8;
typedef __attribute__((ext_vector_type(4))) float f32x4;

// ws layout (bytes):
// dinv   [0,        400000)
// cnt    [400000,   800000)
// off    [800000,  1200000)
// part   [1200000, 1202048)
// sums8  [1202048, 1210240)   8 x 256 floats ([0..127]=s, [128..255]=s2)
// esrc   [1210368, 7610368)   src per CSR slot
// hist   [7610368, 20410368)  12.8 MB (4 groups x 64 chunks x 12500 words)
// xh     [20410368,46010368)  x bf16 packed [NN][64] uints; reused as relu-bf16 rh
// Wht    [46010368,46043136)
// d_out doubles as bf16 agg buffer between gather and gemm.

__device__ __forceinline__ unsigned bf_rne(float f) {
    unsigned u = __float_as_uint(f);
    return (u + 0x7fffu + ((u >> 16) & 1u)) >> 16;
}
__device__ __forceinline__ unsigned pk2(float lo, float hi) {
    return bf_rne(lo) | (bf_rne(hi) << 16);
}

// ---- kernel 1: heterogeneous: blocks<256 LDS histograms; blocks>=256 x->bf16 ----
__global__ __launch_bounds__(1024) void k_hist(const int* __restrict__ ei,
                                               unsigned* __restrict__ hist,
                                               const float* __restrict__ x,
                                               unsigned* __restrict__ xh) {
    __shared__ unsigned loc[HSTR];  // 50 KB
    if (blockIdx.x < 256) {
        const int g = blockIdx.x & 3;
        const int t = blockIdx.x >> 2;
        const int lo = g * GSZ4, hi = lo + GSZ4;
        for (int j = threadIdx.x; j < HSTR; j += 1024) loc[j] = 0u;
        __syncthreads();
        const int end = t * CH + CH;
        for (int i = t * CH + threadIdx.x; i < end; i += 1024) {
            int r = __builtin_nontemporal_load(ei + i);
            int c = __builtin_nontemporal_load(ei + NE + i);
            if (r != c) {
                if (c >= lo && c < hi) {
                    int q = c - lo;
                    atomicAdd(&loc[q >> 2], 1u << ((q & 3) << 3));
                }
                if (r >= lo && r < hi) {
                    int q = r - lo;
                    atomicAdd(&loc[HW8 + (q >> 2)], 1u << ((q & 3) << 3));
                }
            }
        }
        __syncthreads();
        unsigned* dst = hist + (unsigned)(g * NCH + t) * HSTR;
        for (int j = threadIdx.x; j < HSTR; j += 1024) dst[j] = loc[j];
    } else {
        // x -> bf16 packed, f32x4 (16B) loads, grid-stride
        int idx = (blockIdx.x - 256) * 1024 + threadIdx.x;
        const int stride = NCVT * 1024;
        for (; idx < NN * 32; idx += stride) {
            f32x4 v = __builtin_nontemporal_load((const f32x4*)x + idx);
            uint2 o;
            o.x = pk2(v.x, v.y);
            o.y = pk2(v.z, v.w);
            ((uint2*)xh)[idx] = o;
        }
    }
}

// ---- kernel 2: reduce hists -> cnt, dinv; chunk prefixes; scan1; cvtw; zero ----
__global__ __launch_bounds__(256) void k_reduce(unsigned* __restrict__ hist,
                                                unsigned* __restrict__ cnt,
                                                float* __restrict__ dinv,
                                                const float* __restrict__ W,
                                                unsigned short* __restrict__ Wht,
                                                unsigned* __restrict__ part,
                                                float* __restrict__ sums8) {
    __shared__ unsigned ps[256];
    int id = blockIdx.x * 256 + threadIdx.x;
    unsigned mysum = 0;
    if (id < 4 * HW8) {
        int g = id / HW8;
        int w = id - g * HW8;
        unsigned base = (unsigned)(g * NCH) * HSTR + w;
        unsigned r0 = 0, r1 = 0, r2 = 0, r3 = 0;
        unsigned s0 = 0, s1 = 0, s2 = 0, s3 = 0;
        for (int t = 0; t < NCH; ++t) {
            unsigned idx = base + (unsigned)t * HSTR;
            unsigned v = hist[idx];
            hist[idx] = r0 | (r1 << 8) | (r2 << 16) | (r3 << 24);  // excl prefix
            r0 += v & 255u; r1 += (v >> 8) & 255u;
            r2 += (v >> 16) & 255u; r3 += v >> 24;
            unsigned d = hist[idx + HW8];
            s0 += d & 255u; s1 += (d >> 8) & 255u;
            s2 += (d >> 16) & 255u; s3 += d >> 24;
        }
        int n0 = 4 * id;
        cnt[n0]     = r0; cnt[n0 + 1] = r1; cnt[n0 + 2] = r2; cnt[n0 + 3] = r3;
        dinv[n0]     = rsqrtf((float)(s0 + 1u));  // +1 self-loop
        dinv[n0 + 1] = rsqrtf((float)(s1 + 1u));
        dinv[n0 + 2] = rsqrtf((float)(s2 + 1u));
        dinv[n0 + 3] = rsqrtf((float)(s3 + 1u));
        mysum = r0 + r1 + r2 + r3;
    } else {
        int i = id - 4 * HW8;
        if (i < D * D) {           // cvtw: W[k][c] -> Wht[c][k]
            int k = i >> 7, c = i & 127;
            Wht[c * D + k] = (unsigned short)bf_rne(W[i]);
        } else if (i < D * D + 2048) {
            sums8[i - D * D] = 0.f;
        }
    }
    if (blockIdx.x < NPART) {  // scan1: per-1024-node chunk sums
        ps[threadIdx.x] = mysum;
        __syncthreads();
        for (int o = 128; o > 0; o >>= 1) {
            if (threadIdx.x < o) ps[threadIdx.x] += ps[threadIdx.x + o];
            __syncthreads();
        }
        if (threadIdx.x == 0) part[blockIdx.x] = ps[0];
    }
}

// ------- scan step: per-node exclusive offsets; each block scans part itself ----
__global__ __launch_bounds__(256) void k_scan3(const unsigned* __restrict__ cnt,
                                               const unsigned* __restrict__ part,
                                               unsigned* __restrict__ off) {
    __shared__ unsigned pp[128];
    __shared__ unsigned s[256];
    const int t = threadIdx.x;
    if (t < 128) pp[t] = (t < NPART) ? part[t] : 0u;
    __syncthreads();
    for (int o = 1; o < 128; o <<= 1) {  // inclusive scan of partials
        unsigned add = (t < 128 && t >= o) ? pp[t - o] : 0u;
        __syncthreads();
        if (t < 128) pp[t] += add;
        __syncthreads();
    }
    const unsigned base = (blockIdx.x == 0) ? 0u : pp[blockIdx.x - 1];

    const int n0 = (blockIdx.x * 256 + t) * 4;
    unsigned c0 = 0, c1 = 0, c2 = 0, c3 = 0;
    if (n0 + 3 < NN) {
        uint4 v = *(const uint4*)&cnt[n0];
        c0 = v.x; c1 = v.y; c2 = v.z; c3 = v.w;
    } else if (n0 < NN) {
        c0 = cnt[n0];
        if (n0 + 1 < NN) c1 = cnt[n0 + 1];
        if (n0 + 2 < NN) c2 = cnt[n0 + 2];
    }
    unsigned mysum = c0 + c1 + c2 + c3;
    s[t] = mysum;
    __syncthreads();
    for (int o = 1; o < 256; o <<= 1) {
        unsigned add = (t >= o) ? s[t - o] : 0u;
        __syncthreads();
        s[t] += add;
        __syncthreads();
    }
    unsigned e = base + s[t] - mysum;
    if (n0 < NN) {
        off[n0] = e;
        if (n0 + 1 < NN) off[n0 + 1] = e + c0;
        if (n0 + 2 < NN) off[n0 + 2] = e + c0 + c1;
        if (n0 + 3 < NN) off[n0 + 3] = e + c0 + c1 + c2;
    }
}

// ---- kernel 3: 4-group scatter via packed 16-bit LDS cursors, 1024 thr ---------
__global__ __launch_bounds__(1024) void k_scatter(const int* __restrict__ ei,
                                                  const unsigned* __restrict__ off,
                                                  const unsigned* __restrict__ hist,
                                                  int* __restrict__ esrc) {
    __shared__ unsigned curs[GSZ4 / 2];  // 50 KB packed
    const int g = blockIdx.x & 3;
    const int t = blockIdx.x >> 2;
    const int lo = g * GSZ4, hi = lo + GSZ4;
    const unsigned* hb = hist + (unsigned)(g * NCH + t) * HSTR;
    for (int j = threadIdx.x; j < GSZ4 / 2; j += 1024) {
        unsigned hv = hb[j >> 1];
        unsigned sh = (j & 1) << 4;  // bytes {0,1} or {2,3}
        unsigned p0 = (hv >> sh) & 255u;
        unsigned p1 = (hv >> (sh + 8)) & 255u;
        curs[j] = p0 | (p1 << 16);
    }
    __syncthreads();
    const int end = t * CH + CH;
    for (int i = t * CH + threadIdx.x; i < end; i += 1024) {
        int r = __builtin_nontemporal_load(ei + i);
        int c = __builtin_nontemporal_load(ei + NE + i);
        if (r == c || c < lo || c >= hi) continue;
        int q = c - lo;
        unsigned sh = (q & 1) << 4;
        unsigned old = atomicAdd(&curs[q >> 1], 1u << sh);  // LDS atomic
        unsigned pos = off[c] + ((old >> sh) & 0xffffu);
        esrc[pos] = r;  // L2-local slice, plain store
    }
}

// -------- kernel 4: gather bf16 rows -> bf16 agg: dc*(dc*x_c + sum dr*x_r) ------
__global__ __launch_bounds__(256) void k_gather(const unsigned* __restrict__ xh,
                                                const float* __restrict__ dinv,
                                                const unsigned* __restrict__ off,
                                                const unsigned* __restrict__ cnt,
                                                const int* __restrict__ esrc,
                                                unsigned* __restrict__ outh) {
    const int lane = threadIdx.x & 63;
    const int wave = threadIdx.x >> 6;
    const int c = blockIdx.x * 4 + wave;
    if (c >= NN) return;

    const float dc = dinv[c];
    unsigned xc = xh[c * 64 + lane];
    float al = dc * __uint_as_float(xc << 16);
    float ah = dc * __uint_as_float(xc & 0xffff0000u);

    const int base = off[c];
    const int n = cnt[c];
    int i = 0;
    for (; i + 8 <= n; i += 8) {
        int   sv[8];
        float wv[8];
        unsigned pv[8];
        #pragma unroll
        for (int j = 0; j < 8; ++j) sv[j] = esrc[base + i + j];
        #pragma unroll
        for (int j = 0; j < 8; ++j) wv[j] = dinv[sv[j]];
        #pragma unroll
        for (int j = 0; j < 8; ++j) pv[j] = xh[sv[j] * 64 + lane];
        #pragma unroll
        for (int j = 0; j < 8; ++j) {
            al = fmaf(wv[j], __uint_as_float(pv[j] << 16), al);
            ah = fmaf(wv[j], __uint_as_float(pv[j] & 0xffff0000u), ah);
        }
    }
    for (; i + 4 <= n; i += 4) {
        int s0 = esrc[base + i], s1 = esrc[base + i + 1];
        int s2 = esrc[base + i + 2], s3 = esrc[base + i + 3];
        float w0 = dinv[s0], w1 = dinv[s1], w2 = dinv[s2], w3 = dinv[s3];
        unsigned p0 = xh[s0 * 64 + lane], p1 = xh[s1 * 64 + lane];
        unsigned p2 = xh[s2 * 64 + lane], p3 = xh[s3 * 64 + lane];
        al = fmaf(w0, __uint_as_float(p0 << 16), al);
        ah = fmaf(w0, __uint_as_float(p0 & 0xffff0000u), ah);
        al = fmaf(w1, __uint_as_float(p1 << 16), al);
        ah = fmaf(w1, __uint_as_float(p1 & 0xffff0000u), ah);
        al = fmaf(w2, __uint_as_float(p2 << 16), al);
        ah = fmaf(w2, __uint_as_float(p2 & 0xffff0000u), ah);
        al = fmaf(w3, __uint_as_float(p3 << 16), al);
        ah = fmaf(w3, __uint_as_float(p3 & 0xffff0000u), ah);
    }
    for (; i < n; ++i) {
        int s0 = esrc[base + i];
        float w0 = dinv[s0];
        unsigned p0 = xh[s0 * 64 + lane];
        al = fmaf(w0, __uint_as_float(p0 << 16), al);
        ah = fmaf(w0, __uint_as_float(p0 & 0xffff0000u), ah);
    }
    outh[c * 64 + lane] = pk2(al * dc, ah * dc);  // bf16 agg
}

// ---- kernel 5: MFMA GEMM (bf16 A direct) + bias + ReLU -> bf16 rh + BN stats ---
__global__ __launch_bounds__(256, 1) void k_gemm(const unsigned short* __restrict__ aggh,
                                                 unsigned short* __restrict__ rh,
                                                 const unsigned short* __restrict__ Wht,
                                                 const float* __restrict__ b,
                                                 float* __restrict__ sums8) {
    __shared__ float sums_lds[256];
    const int lane = threadIdx.x & 63;
    const int wv = threadIdx.x >> 6;
    const int l15 = lane & 15, l4 = lane >> 4;

    if (threadIdx.x < 256) sums_lds[threadIdx.x] = 0.f;
    __syncthreads();

    short8 bfr[8][4];
    #pragma unroll
    for (int n = 0; n < 8; ++n)
        #pragma unroll
        for (int kk = 0; kk < 4; ++kk)
            bfr[n][kk] = *(const short8*)(Wht + (n * 16 + l15) * D + kk * 32 + l4 * 8);

    float bias8[8];
    #pragma unroll
    for (int n = 0; n < 8; ++n) bias8[n] = b[n * 16 + l15];

    float sl[8], s2l[8];
    #pragma unroll
    for (int n = 0; n < 8; ++n) { sl[n] = 0.f; s2l[n] = 0.f; }

    const int gw = blockIdx.x * 4 + wv;
    #pragma unroll
    for (int t = 0; t < 2; ++t) {
        const int tile = gw * 2 + t;
        if (tile < NN / 16) {
            const int row0 = tile * 16;
            short8 af[4];
            #pragma unroll
            for (int kk = 0; kk < 4; ++kk)
                af[kk] = *(const short8*)(aggh + (row0 + l15) * D + kk * 32 + l4 * 8);
            f32x4 acc[8];
            #pragma unroll
            for (int n = 0; n < 8; ++n) acc[n] = (f32x4){0.f, 0.f, 0.f, 0.f};
            #pragma unroll
            for (int n = 0; n < 8; ++n)
                #pragma unroll
                for (int kk = 0; kk < 4; ++kk)
                    acc[n] = __builtin_amdgcn_mfma_f32_16x16x32_bf16(af[kk], bfr[n][kk],
                                                                     acc[n], 0, 0, 0);
            #pragma unroll
            for (int n = 0; n < 8; ++n)
                #pragma unroll
                for (int j = 0; j < 4; ++j) {
                    int row = row0 + l4 * 4 + j;
                    float v = fmaxf(acc[n][j] + bias8[n], 0.f);
                    rh[row * D + n * 16 + l15] = (unsigned short)bf_rne(v);
                    sl[n] += v;
                    s2l[n] = fmaf(v, v, s2l[n]);
                }
        }
    }

    #pragma unroll
    for (int n = 0; n < 8; ++n) {
        float a = sl[n], q = s2l[n];
        a += __shfl_xor(a, 16); a += __shfl_xor(a, 32);
        q += __shfl_xor(q, 16); q += __shfl_xor(q, 32);
        if (l4 == 0) {
            atomicAdd(&sums_lds[n * 16 + l15], a);
            atomicAdd(&sums_lds[128 + n * 16 + l15], q);
        }
    }
    __syncthreads();
    if (threadIdx.x < 256)
        unsafeAtomicAdd(&sums8[(blockIdx.x & 7) * 256 + threadIdx.x],
                        sums_lds[threadIdx.x]);
}

// ------------- kernel 6: out = rh_bf16 * scale + shift (BN affine) --------------
__global__ __launch_bounds__(256) void k_apply(const unsigned* __restrict__ rh,
                                               float* __restrict__ out,
                                               const float* __restrict__ gamma,
                                               const float* __restrict__ beta,
                                               const float* __restrict__ sums8) {
    const float invN = 1.f / (float)NN;
    const int tid = blockIdx.x * blockDim.x + threadIdx.x;
    const int stride = gridDim.x * blockDim.x;
    const int c4 = (tid & 31) * 4;

    float4 s4 = make_float4(0.f, 0.f, 0.f, 0.f);
    float4 q4 = make_float4(0.f, 0.f, 0.f, 0.f);
    #pragma unroll
    for (int k = 0; k < 8; ++k) {
        float4 a = *(const float4*)&sums8[k * 256 + c4];
        float4 q = *(const float4*)&sums8[k * 256 + 128 + c4];
        s4.x += a.x; s4.y += a.y; s4.z += a.z; s4.w += a.w;
        q4.x += q.x; q4.y += q.y; q4.z += q.z; q4.w += q.w;
    }
    float4 g4 = *(const float4*)&gamma[c4];
    float4 be = *(const float4*)&beta[c4];

    float mx = s4.x * invN, my = s4.y * invN, mz = s4.z * invN, mw = s4.w * invN;
    float scx = g4.x * rsqrtf(fmaxf(q4.x * invN - mx * mx, 0.f) + BN_EPS);
    float scy = g4.y * rsqrtf(fmaxf(q4.y * invN - my * my, 0.f) + BN_EPS);
    float scz = g4.z * rsqrtf(fmaxf(q4.z * invN - mz * mz, 0.f) + BN_EPS);
    float scw = g4.w * rsqrtf(fmaxf(q4.w * invN - mw * mw, 0.f) + BN_EPS);
    float shx = be.x - mx * scx, shy = be.y - my * scy;
    float shz = be.z - mz * scz, shw = be.w - mw * scw;

    for (int idx = tid; idx < NN * (D / 4); idx += stride) {
        const int row = idx >> 5;
        uint2 p = *(const uint2*)&rh[row * 64 + (tid & 31) * 2];
        float4 a;
        a.x = __uint_as_float(p.x << 16);
        a.y = __uint_as_float(p.x & 0xffff0000u);
        a.z = __uint_as_float(p.y << 16);
        a.w = __uint_as_float(p.y & 0xffff0000u);
        a.x = a.x * scx + shx;
        a.y = a.y * scy + shy;
        a.z = a.z * scz + shz;
        a.w = a.w * scw + shw;
        ((float4*)out)[idx] = a;
    }
}

extern "C" void kernel_launch(void* const* d_in, const int* in_sizes, int n_in,
                              void* d_out, int out_size, void* d_ws, size_t ws_size,
                              hipStream_t stream) {
    const float* x     = (const float*)d_in[0];
    const int*   ei    = (const int*)d_in[1];
    const float* W     = (const float*)d_in[2];
    const float* b     = (const float*)d_in[3];
    const float* gamma = (const float*)d_in[4];
    const float* beta  = (const float*)d_in[5];
    float*       out   = (float*)d_out;

    char* ws = (char*)d_ws;
    float*          dinv  = (float*)ws;
    unsigned*       cnt   = (unsigned*)(ws + 400000);
    unsigned*       off   = (unsigned*)(ws + 800000);
    unsigned*       part  = (unsigned*)(ws + 1200000);
    float*          sums8 = (float*)(ws + 1202048);
    int*            esrc  = (int*)(ws + 1210368);
    unsigned*       hist  = (unsigned*)(ws + 7610368);   // 12.8 MB
    unsigned*       xh    = (unsigned*)(ws + 20410368);  // 25.6 MB; rh after gather
    unsigned short* Wht   = (unsigned short*)(ws + 46010368);

    k_hist<<<256 + NCVT, 1024, 0, stream>>>(ei, hist, x, xh);
    k_reduce<<<(4 * HW8 + D * D + 2048 + 255) / 256, 256, 0, stream>>>(hist, cnt, dinv, W, Wht, part, sums8);
    k_scan3<<<NPART, 256, 0, stream>>>(cnt, part, off);
    k_scatter<<<NCH * 4, 1024, 0, stream>>>(ei, off, hist, esrc);
    k_gather<<<25000, 256, 0, stream>>>(xh, dinv, off, cnt, esrc, (unsigned*)out);
    k_gemm<<<782, 256, 0, stream>>>((const unsigned short*)out, (unsigned short*)xh, Wht, b, sums8);
    k_apply<<<2048, 256, 0, stream>>>(xh, out, gamma, beta, sums8);
}